// Round 4
// baseline (114.619 us; speedup 1.0000x reference)
//
#include <hip/hip_runtime.h>
#include <hip/hip_bf16.h>
#include <math.h>

// Problem dims (fixed)
#define BB 4
#define TT 4096
#define DM 1024
#define DS 256
#define MROWS (BB*TT)        // 16384

// Scan chunking
#define LCH 32
#define NCH (TT/LCH)         // 128

// GEMM tiling: 128x64 tile, BK=32, 2 waves (rows split), per-wave 64x64
#define BM 128
#define BN 64
#define BK 32

typedef __attribute__((ext_vector_type(8))) short short8v;
typedef __attribute__((ext_vector_type(8))) unsigned short ushort8v;
typedef __attribute__((ext_vector_type(4))) float float4v;

__device__ __forceinline__ unsigned short bf16_bits(float f) {
    union { __hip_bfloat16 b; unsigned short u; } cv;
    cv.b = __float2bfloat16(f);
    return cv.u;
}
__device__ __forceinline__ float bits_to_f32(unsigned short h) {
    union { unsigned int u; float f; } cv; cv.u = ((unsigned int)h) << 16; return cv.f;
}
__device__ __forceinline__ void split_bf16(float a, unsigned short& hi, unsigned short& lo) {
    hi = bf16_bits(a);
    lo = bf16_bits(a - bits_to_f32(hi));
}
__device__ __forceinline__ float sigmoidf_dev(float x) {
    return 1.0f / (1.0f + expf(-x));
}

// async global->LDS, 16 bytes per lane, linear dest
__device__ __forceinline__ void gload16(const void* g, void* l) {
    __builtin_amdgcn_global_load_lds(
        (const __attribute__((address_space(1))) void*)g,
        (__attribute__((address_space(3))) void*)l, 16, 0, 0);
}

// ---------------- weight pre-split: W[K][N] fp32 -> Bt{hi,lo}[N][K] bf16 ----------------
__global__ __launch_bounds__(256) void split_weight(
    const float* __restrict__ W, unsigned short* __restrict__ Bh,
    unsigned short* __restrict__ Bl, int K, int N)
{
    int idx = blockIdx.x * 256 + threadIdx.x;
    int n = idx / K, k = idx - n * K;
    float a = W[(size_t)k * N + n];
    unsigned short hi, lo;
    split_bf16(a, hi, lo);
    Bh[idx] = hi;
    Bl[idx] = lo;
}

// ---------------- split-bf16 MFMA GEMM ----------------
// C[M][N] = (A[M][K] @ Bt[N][K]^T + bias[n]) * scale[n]
// AF32=true : A is fp32 global, staged as f32, split hi/lo at fragment read (GEMM1)
// AF32=false: A pre-split bf16 hi/lo (GEMM2)
// 128 threads (2 waves), grid flat (XCD-swizzled), tile BM=128 x BN=64, BK=32.
//
// LDS swizzles (source-preswizzled for linear global_load_lds dest, same XOR on read):
//   A-f32 tile [128 rows][8 x 16B chunks]  : chunk' = chunk ^ (row & 7)
//   bf16 tiles [rows][4 x 16B chunks]      : chunk' = chunk ^ ((row >> 1) & 3)
// Both give 2-way-max bank aliasing on ds_read_b128 (free).
template<bool AF32>
__global__ __launch_bounds__(128) void mfma_gemm(
    const float* __restrict__ Af,
    const unsigned short* __restrict__ Ahg, const unsigned short* __restrict__ Alg,
    const unsigned short* __restrict__ Bhg, const unsigned short* __restrict__ Blg,
    float* __restrict__ C, int M, int N, int K, int GN,
    const float* __restrict__ bias, const float* __restrict__ scale)
{
    __shared__ char smem[49152];

    // XCD-aware block swizzle (grid % 8 == 0 for both GEMMs)
    const int nwg = gridDim.x;
    const int bid = blockIdx.x;
    const int wgid = (bid & 7) * (nwg >> 3) + (bid >> 3);
    const int bm = wgid / GN;
    const int bn = wgid - bm * GN;

    const int tid  = threadIdx.x;
    const int lane = tid & 63;
    const int wv   = tid >> 6;          // 0..1 : rows wv*64 .. wv*64+63
    const int lrow = lane & 15;
    const int q16  = lane >> 4;         // 0..3 k-chunk group

    // LDS carve (byte offsets), double-buffered
    // AF32:  Af32[q] @ q*16384 (16KB)            | Bh[q] @ 32768+q*4096 | Bl[q] @ 40960+q*4096
    // !AF32: Ah[q] @ q*8192, Al[q] @ 16384+q*8192| same B
    char* const sb = smem;

    const int NT = K / BK;
    float4v acc[4][4] = {};

#define STAGE(T, Q)                                                                \
    do {                                                                           \
        const int k0_ = (T) * BK;                                                  \
        if constexpr (AF32) {                                                      \
            _Pragma("unroll")                                                      \
            for (int p = 0; p < 8; p++) {                                          \
                int c = tid + p * 128, row = c >> 3, cc = c & 7;                   \
                const float* g = Af + (size_t)(bm * BM + row) * K + k0_            \
                                   + ((cc ^ (row & 7)) << 2);                      \
                gload16(g, sb + (Q) * 16384 + c * 16);                             \
            }                                                                      \
        } else {                                                                   \
            _Pragma("unroll")                                                      \
            for (int p = 0; p < 4; p++) {                                          \
                int c = tid + p * 128, row = c >> 2, cc = c & 3;                   \
                size_t go = (size_t)(bm * BM + row) * K + k0_                      \
                            + ((cc ^ ((row >> 1) & 3)) << 3);                      \
                gload16(Ahg + go, sb + (Q) * 8192 + c * 16);                       \
                gload16(Alg + go, sb + 16384 + (Q) * 8192 + c * 16);               \
            }                                                                      \
        }                                                                          \
        _Pragma("unroll")                                                          \
        for (int p = 0; p < 2; p++) {                                              \
            int c = tid + p * 128, row = c >> 2, cc = c & 3;                       \
            size_t go = (size_t)(bn * BN + row) * K + k0_                          \
                        + ((cc ^ ((row >> 1) & 3)) << 3);                          \
            gload16(Bhg + go, sb + 32768 + (Q) * 4096 + c * 16);                   \
            gload16(Blg + go, sb + 40960 + (Q) * 4096 + c * 16);                   \
        }                                                                          \
    } while (0)

    STAGE(0, 0);
    __syncthreads();

    for (int t = 0; t < NT; ++t) {
        const int Q = t & 1;
        if (t + 1 < NT) STAGE(t + 1, Q ^ 1);

        // ---- fragments ----
        short8v ah[4], al[4], bh[4], bl[4];
#pragma unroll
        for (int i = 0; i < 4; i++) {
            int row = wv * 64 + i * 16 + lrow;
            if constexpr (AF32) {
                const char* base = sb + Q * 16384 + row * 128;
                int s = row & 7;
                float4 fa = *(const float4*)(base + (((2 * q16)     ^ s) << 4));
                float4 fb = *(const float4*)(base + (((2 * q16 + 1) ^ s) << 4));
                float f[8] = {fa.x, fa.y, fa.z, fa.w, fb.x, fb.y, fb.z, fb.w};
#pragma unroll
                for (int e = 0; e < 8; e++) {
                    unsigned short hu, lu;
                    split_bf16(f[e], hu, lu);
                    ah[i][e] = (short)hu; al[i][e] = (short)lu;
                }
            } else {
                int slot = (q16 ^ ((row >> 1) & 3)) << 4;
                ah[i] = *(const short8v*)(sb + Q * 8192 + row * 64 + slot);
                al[i] = *(const short8v*)(sb + 16384 + Q * 8192 + row * 64 + slot);
            }
        }
#pragma unroll
        for (int j = 0; j < 4; j++) {
            int row = j * 16 + lrow;
            int slot = (q16 ^ ((row >> 1) & 3)) << 4;
            bh[j] = *(const short8v*)(sb + 32768 + Q * 4096 + row * 64 + slot);
            bl[j] = *(const short8v*)(sb + 40960 + Q * 4096 + row * 64 + slot);
        }

        // ---- MFMA: 3-pass split ----
#pragma unroll
        for (int i = 0; i < 4; i++)
#pragma unroll
            for (int j = 0; j < 4; j++) {
                acc[i][j] = __builtin_amdgcn_mfma_f32_16x16x32_bf16(ah[i], bh[j], acc[i][j], 0, 0, 0);
                acc[i][j] = __builtin_amdgcn_mfma_f32_16x16x32_bf16(ah[i], bl[j], acc[i][j], 0, 0, 0);
                acc[i][j] = __builtin_amdgcn_mfma_f32_16x16x32_bf16(al[i], bh[j], acc[i][j], 0, 0, 0);
            }

        __syncthreads();
    }

    // ---- epilogue ----
#pragma unroll
    for (int j = 0; j < 4; j++) {
        int col = bn * BN + j * 16 + lrow;
        float bi = bias[col];
        float sc = scale ? scale[col] : 1.0f;
#pragma unroll
        for (int i = 0; i < 4; i++) {
            int r0 = bm * BM + wv * 64 + i * 16 + q16 * 4;
#pragma unroll
            for (int reg = 0; reg < 4; reg++) {
                C[(size_t)(r0 + reg) * N + col] = (acc[i][j][reg] + bi) * sc;
            }
        }
    }
#undef STAGE
}

// ---------------- scan kernels ----------------
__global__ __launch_bounds__(256) void scan_partial(
    const float* __restrict__ gu, const float* __restrict__ lam, float* __restrict__ csum)
{
    const int s = threadIdx.x;
    const int chunk = blockIdx.x;
    const int b = blockIdx.y;
    const float d = sigmoidf_dev(lam[s]);
    const float* p = gu + ((size_t)b * TT + (size_t)chunk * LCH) * DS + s;
    float h = 0.0f;
#pragma unroll
    for (int t = 0; t < LCH; t++) h = fmaf(d, h, p[(size_t)t * DS]);
    csum[((size_t)b * NCH + chunk) * DS + s] = h;
}

__global__ __launch_bounds__(256) void carry_scan(
    const float* __restrict__ csum, const float* __restrict__ state,
    const float* __restrict__ lam, float* __restrict__ carry, float* __restrict__ hlast)
{
    const int s = threadIdx.x;
    const int b = blockIdx.x;
    const float d = sigmoidf_dev(lam[s]);
    float dL = d;
#pragma unroll
    for (int i = 0; i < 5; i++) dL *= dL;   // d^32
    float H = state[(size_t)b * DS + s];
#pragma unroll 8
    for (int k = 0; k < NCH; k++) {
        carry[((size_t)b * NCH + k) * DS + s] = H;
        H = fmaf(dL, H, csum[((size_t)b * NCH + k) * DS + s]);
    }
    hlast[(size_t)b * DS + s] = H;
}

__global__ __launch_bounds__(256) void scan_final(
    const float* __restrict__ gu, const float* __restrict__ lam,
    const float* __restrict__ carry,
    unsigned short* __restrict__ hhi, unsigned short* __restrict__ hlo)
{
    const int s = threadIdx.x;
    const int chunk = blockIdx.x;
    const int b = blockIdx.y;
    const float d = sigmoidf_dev(lam[s]);
    const size_t base = ((size_t)b * TT + (size_t)chunk * LCH) * DS + s;
    const float* p = gu + base;
    unsigned short* ph = hhi + base;
    unsigned short* pl = hlo + base;
    float h = carry[((size_t)b * NCH + chunk) * DS + s];
#pragma unroll
    for (int t = 0; t < LCH; t++) {
        h = fmaf(d, h, p[(size_t)t * DS]);
        unsigned short hi, lo;
        split_bf16(h, hi, lo);
        ph[(size_t)t * DS] = hi;
        pl[(size_t)t * DS] = lo;
    }
}

extern "C" void kernel_launch(void* const* d_in, const int* in_sizes, int n_in,
                              void* d_out, int out_size, void* d_ws, size_t ws_size,
                              hipStream_t stream) {
    const float* x     = (const float*)d_in[0];
    const float* state = (const float*)d_in[1];
    const float* W_in  = (const float*)d_in[2];
    const float* b_in  = (const float*)d_in[3];
    const float* lam   = (const float*)d_in[4];
    const float* gamma = (const float*)d_in[5];
    const float* W_out = (const float*)d_in[6];
    const float* b_out = (const float*)d_in[7];

    float* y     = (float*)d_out;
    float* hlast = y + (size_t)MROWS * DM;

    char* ws = (char*)d_ws;
    const size_t MB = 1024 * 1024;
    float*          gu    = (float*)(ws);                        // 16 MB
    float*          csum  = (float*)(ws + 16 * MB);              // 512 KB
    float*          carry = (float*)(ws + 16 * MB + 512 * 1024); // 512 KB
    unsigned short* hhi   = (unsigned short*)(ws + 17 * MB);     // 8 MB
    unsigned short* hlo   = (unsigned short*)(ws + 25 * MB);     // 8 MB
    unsigned short* w1hi  = (unsigned short*)(ws + 33 * MB);     // [DS][DM]
    unsigned short* w1lo  = (unsigned short*)(ws + 33 * MB + 512 * 1024);
    unsigned short* w2hi  = (unsigned short*)(ws + 34 * MB);     // [DM][DS]
    unsigned short* w2lo  = (unsigned short*)(ws + 34 * MB + 512 * 1024);

    split_weight<<<dim3((DS * DM) / 256), dim3(256), 0, stream>>>(W_in,  w1hi, w1lo, DM, DS);
    split_weight<<<dim3((DS * DM) / 256), dim3(256), 0, stream>>>(W_out, w2hi, w2lo, DS, DM);

    // GEMM1: gu = gamma * (x @ W_in + b_in)  [16384 x 256], K=1024, grid 128*4=512
    mfma_gemm<true><<<dim3((MROWS / BM) * (DS / BN)), dim3(128), 0, stream>>>(
        x, nullptr, nullptr, w1hi, w1lo, gu, MROWS, DS, DM, DS / BN, b_in, gamma);

    scan_partial<<<dim3(NCH, BB), dim3(256), 0, stream>>>(gu, lam, csum);
    carry_scan<<<dim3(BB), dim3(256), 0, stream>>>(csum, state, lam, carry, hlast);
    scan_final<<<dim3(NCH, BB), dim3(256), 0, stream>>>(gu, lam, carry, hhi, hlo);

    // GEMM2: y = h @ W_out + b_out  [16384 x 1024], K=256, grid 128*16=2048
    mfma_gemm<false><<<dim3((MROWS / BM) * (DM / BN)), dim3(128), 0, stream>>>(
        nullptr, hhi, hlo, w2hi, w2lo, y, MROWS, DM, DS, DM / BN, b_out, nullptr);
}

// Round 5
// 100.893 us; speedup vs baseline: 1.1360x; 1.1360x over previous
//
#include <hip/hip_runtime.h>
#include <hip/hip_bf16.h>
#include <math.h>

// Problem dims (fixed)
#define BB 4
#define TT 4096
#define DM 1024
#define DS 256
#define MROWS (BB*TT)        // 16384

// Scan chunking
#define LCH 32
#define NCH (TT/LCH)         // 128

#define BK 32
#define BM 128

typedef __attribute__((ext_vector_type(8))) short short8v;
typedef __attribute__((ext_vector_type(4))) float float4v;

__device__ __forceinline__ unsigned short bf16_bits(float f) {
    union { __hip_bfloat16 b; unsigned short u; } cv;
    cv.b = __float2bfloat16(f);
    return cv.u;
}
__device__ __forceinline__ float bits_to_f32(unsigned short h) {
    union { unsigned int u; float f; } cv; cv.u = ((unsigned int)h) << 16; return cv.f;
}
__device__ __forceinline__ void split_bf16(float a, unsigned short& hi, unsigned short& lo) {
    hi = bf16_bits(a);
    lo = bf16_bits(a - bits_to_f32(hi));
}
__device__ __forceinline__ float sigmoidf_dev(float x) {
    return 1.0f / (1.0f + expf(-x));
}

// async global->LDS, 16 bytes per lane; dest must be uniform + lane*16 (m104)
__device__ __forceinline__ void gload16(const void* g, void* l) {
    __builtin_amdgcn_global_load_lds(
        (const __attribute__((address_space(1))) void*)g,
        (__attribute__((address_space(3))) void*)l, 16, 0, 0);
}

// ---------------- weight pre-split: W[K][N] fp32 -> Bt{hi,lo}[N][K] bf16 ----------------
__global__ __launch_bounds__(256) void split_weight(
    const float* __restrict__ W, unsigned short* __restrict__ Bh,
    unsigned short* __restrict__ Bl, int K, int N)
{
    int idx = blockIdx.x * 256 + threadIdx.x;
    int n = idx / K, k = idx - n * K;
    float a = W[(size_t)k * N + n];
    unsigned short hi, lo;
    split_bf16(a, hi, lo);
    Bh[idx] = hi;
    Bl[idx] = lo;
}

// ---------------- split-bf16 MFMA GEMM (m97 structure) ----------------
// C[M][N] = (A[M][K] @ Bt[N][K]^T + bias[n]) * scale[n]
// 256 threads, 4 waves 2x2. Wave tile: 64 x (BN/2).
// AF32=true : A fp32 staged to LDS, split hi/lo at fragment read (GEMM1)
// AF32=false: A pre-split bf16 hi/lo in global (GEMM2)
// Swizzles (pre-swizzled global source, same XOR on LDS read; LDS dest linear):
//   A-f32 [128 rows][8 chunks16B]: chunk' = chunk ^ (row&7)
//   bf16  [rows][4 chunks16B]    : chunk' = chunk ^ ((row>>1)&3)
template<bool AF32, int BN>
__global__ __launch_bounds__(256) void mfma_gemm(
    const float* __restrict__ Af,
    const unsigned short* __restrict__ Ahg, const unsigned short* __restrict__ Alg,
    const unsigned short* __restrict__ Bhg, const unsigned short* __restrict__ Blg,
    float* __restrict__ C, int M, int N, int K, int GN,
    const float* __restrict__ bias, const float* __restrict__ scale)
{
    constexpr int BHALF = BN * 64;                 // bytes of one B half (hi or lo)
    constexpr int BUFB  = 16384 + 2 * BHALF;       // bytes per pipeline buffer
    constexpr int NF    = BN / 32;                 // B frags per wave
    __shared__ char smem[2 * BUFB];

    // XCD-aware block swizzle (grid % 8 == 0)
    const int nwg = gridDim.x;
    const int bid = blockIdx.x;
    const int wgid = (bid & 7) * (nwg >> 3) + (bid >> 3);
    const int bm = wgid / GN;
    const int bn = wgid - bm * GN;

    const int tid  = threadIdx.x;
    const int lane = tid & 63;
    const int wv   = tid >> 6;
    const int wr   = wv >> 1;            // wave row: 0..1 (64 rows)
    const int wc   = wv & 1;             // wave col: 0..1 (BN/2 cols)
    const int lrow = lane & 15;
    const int q16  = lane >> 4;          // 0..3

    const int NT = K / BK;
    float4v acc[4][NF] = {};

#define STAGE(T, Q)                                                               \
    do {                                                                          \
        const int k0_ = (T) * BK;                                                 \
        char* base_ = smem + (Q) * BUFB;                                          \
        if constexpr (AF32) {                                                     \
            _Pragma("unroll")                                                     \
            for (int p = 0; p < 4; p++) {                                         \
                int c = tid + p * 256, row = c >> 3, cc = c & 7;                  \
                const float* g = Af + (size_t)(bm * BM + row) * K + k0_           \
                                   + ((cc ^ (row & 7)) << 2);                     \
                gload16(g, base_ + c * 16);                                       \
            }                                                                     \
        } else {                                                                  \
            _Pragma("unroll")                                                     \
            for (int p = 0; p < 2; p++) {                                         \
                int c = tid + p * 256, row = c >> 2, cc = c & 3;                  \
                size_t go = (size_t)(bm * BM + row) * K + k0_                     \
                            + ((cc ^ ((row >> 1) & 3)) << 3);                     \
                gload16(Ahg + go, base_ + c * 16);                                \
                gload16(Alg + go, base_ + 8192 + c * 16);                         \
            }                                                                     \
        }                                                                         \
        _Pragma("unroll")                                                         \
        for (int p = 0; p < BN / 64; p++) {                                       \
            int c = tid + p * 256, row = c >> 2, cc = c & 3;                      \
            size_t go = (size_t)(bn * BN + row) * K + k0_                         \
                        + ((cc ^ ((row >> 1) & 3)) << 3);                         \
            gload16(Bhg + go, base_ + 16384 + c * 16);                            \
            gload16(Blg + go, base_ + 16384 + BHALF + c * 16);                    \
        }                                                                         \
    } while (0)

    STAGE(0, 0);
    __syncthreads();

    for (int t = 0; t < NT; ++t) {
        const int Q = t & 1;
        if (t + 1 < NT) STAGE(t + 1, Q ^ 1);

        char* const rb = smem + Q * BUFB;

        // ---- fragments ----
        short8v ah[4], al[4], bh[NF], bl[NF];
#pragma unroll
        for (int i = 0; i < 4; i++) {
            int row = wr * 64 + i * 16 + lrow;
            if constexpr (AF32) {
                const char* ab = rb + row * 128;
                int s = row & 7;
                float4 fa = *(const float4*)(ab + (((2 * q16)     ^ s) << 4));
                float4 fb = *(const float4*)(ab + (((2 * q16 + 1) ^ s) << 4));
                float f[8] = {fa.x, fa.y, fa.z, fa.w, fb.x, fb.y, fb.z, fb.w};
#pragma unroll
                for (int e = 0; e < 8; e++) {
                    unsigned short hu, lu;
                    split_bf16(f[e], hu, lu);
                    ah[i][e] = (short)hu; al[i][e] = (short)lu;
                }
            } else {
                int slot = (q16 ^ ((row >> 1) & 3)) << 4;
                ah[i] = *(const short8v*)(rb + row * 64 + slot);
                al[i] = *(const short8v*)(rb + 8192 + row * 64 + slot);
            }
        }
#pragma unroll
        for (int j = 0; j < NF; j++) {
            int row = wc * (BN / 2) + j * 16 + lrow;
            int slot = (q16 ^ ((row >> 1) & 3)) << 4;
            bh[j] = *(const short8v*)(rb + 16384 + row * 64 + slot);
            bl[j] = *(const short8v*)(rb + 16384 + BHALF + row * 64 + slot);
        }

        // ---- MFMA: 3-pass split-bf16 ----
#pragma unroll
        for (int i = 0; i < 4; i++)
#pragma unroll
            for (int j = 0; j < NF; j++) {
                acc[i][j] = __builtin_amdgcn_mfma_f32_16x16x32_bf16(ah[i], bh[j], acc[i][j], 0, 0, 0);
                acc[i][j] = __builtin_amdgcn_mfma_f32_16x16x32_bf16(ah[i], bl[j], acc[i][j], 0, 0, 0);
                acc[i][j] = __builtin_amdgcn_mfma_f32_16x16x32_bf16(al[i], bh[j], acc[i][j], 0, 0, 0);
            }

        __syncthreads();
    }

    // ---- epilogue ----
#pragma unroll
    for (int j = 0; j < NF; j++) {
        int col = bn * BN + wc * (BN / 2) + j * 16 + lrow;
        float bi = bias[col];
        float sc = scale ? scale[col] : 1.0f;
#pragma unroll
        for (int i = 0; i < 4; i++) {
            int r0 = bm * BM + wr * 64 + i * 16 + q16 * 4;
#pragma unroll
            for (int reg = 0; reg < 4; reg++) {
                C[(size_t)(r0 + reg) * N + col] = (acc[i][j][reg] + bi) * sc;
            }
        }
    }
#undef STAGE
}

// ---------------- scan kernels ----------------
__global__ __launch_bounds__(256) void scan_partial(
    const float* __restrict__ gu, const float* __restrict__ lam, float* __restrict__ csum)
{
    const int s = threadIdx.x;
    const int chunk = blockIdx.x;
    const int b = blockIdx.y;
    const float d = sigmoidf_dev(lam[s]);
    const float* p = gu + ((size_t)b * TT + (size_t)chunk * LCH) * DS + s;
    float h = 0.0f;
#pragma unroll
    for (int t = 0; t < LCH; t++) h = fmaf(d, h, p[(size_t)t * DS]);
    csum[((size_t)b * NCH + chunk) * DS + s] = h;
}

__global__ __launch_bounds__(256) void carry_scan(
    const float* __restrict__ csum, const float* __restrict__ state,
    const float* __restrict__ lam, float* __restrict__ carry, float* __restrict__ hlast)
{
    const int s = threadIdx.x;
    const int b = blockIdx.x;
    const float d = sigmoidf_dev(lam[s]);
    float dL = d;
#pragma unroll
    for (int i = 0; i < 5; i++) dL *= dL;   // d^32
    float H = state[(size_t)b * DS + s];
#pragma unroll 8
    for (int k = 0; k < NCH; k++) {
        carry[((size_t)b * NCH + k) * DS + s] = H;
        H = fmaf(dL, H, csum[((size_t)b * NCH + k) * DS + s]);
    }
    hlast[(size_t)b * DS + s] = H;
}

__global__ __launch_bounds__(256) void scan_final(
    const float* __restrict__ gu, const float* __restrict__ lam,
    const float* __restrict__ carry,
    unsigned short* __restrict__ hhi, unsigned short* __restrict__ hlo)
{
    const int s = threadIdx.x;
    const int chunk = blockIdx.x;
    const int b = blockIdx.y;
    const float d = sigmoidf_dev(lam[s]);
    const size_t base = ((size_t)b * TT + (size_t)chunk * LCH) * DS + s;
    const float* p = gu + base;
    unsigned short* ph = hhi + base;
    unsigned short* pl = hlo + base;
    float h = carry[((size_t)b * NCH + chunk) * DS + s];
#pragma unroll
    for (int t = 0; t < LCH; t++) {
        h = fmaf(d, h, p[(size_t)t * DS]);
        unsigned short hi, lo;
        split_bf16(h, hi, lo);
        ph[(size_t)t * DS] = hi;
        pl[(size_t)t * DS] = lo;
    }
}

extern "C" void kernel_launch(void* const* d_in, const int* in_sizes, int n_in,
                              void* d_out, int out_size, void* d_ws, size_t ws_size,
                              hipStream_t stream) {
    const float* x     = (const float*)d_in[0];
    const float* state = (const float*)d_in[1];
    const float* W_in  = (const float*)d_in[2];
    const float* b_in  = (const float*)d_in[3];
    const float* lam   = (const float*)d_in[4];
    const float* gamma = (const float*)d_in[5];
    const float* W_out = (const float*)d_in[6];
    const float* b_out = (const float*)d_in[7];

    float* y     = (float*)d_out;
    float* hlast = y + (size_t)MROWS * DM;

    char* ws = (char*)d_ws;
    const size_t MB = 1024 * 1024;
    float*          gu    = (float*)(ws);                        // 16 MB
    float*          csum  = (float*)(ws + 16 * MB);              // 512 KB
    float*          carry = (float*)(ws + 16 * MB + 512 * 1024); // 512 KB
    unsigned short* hhi   = (unsigned short*)(ws + 17 * MB);     // 8 MB
    unsigned short* hlo   = (unsigned short*)(ws + 25 * MB);     // 8 MB
    unsigned short* w1hi  = (unsigned short*)(ws + 33 * MB);     // [DS][DM]
    unsigned short* w1lo  = (unsigned short*)(ws + 33 * MB + 512 * 1024);
    unsigned short* w2hi  = (unsigned short*)(ws + 34 * MB);     // [DM][DS]
    unsigned short* w2lo  = (unsigned short*)(ws + 34 * MB + 512 * 1024);

    split_weight<<<dim3((DS * DM) / 256), dim3(256), 0, stream>>>(W_in,  w1hi, w1lo, DM, DS);
    split_weight<<<dim3((DS * DM) / 256), dim3(256), 0, stream>>>(W_out, w2hi, w2lo, DS, DM);

    // GEMM1: gu = gamma * (x @ W_in + b_in)  [16384 x 256], K=1024, BN=64 -> grid 512
    mfma_gemm<true, 64><<<dim3((MROWS / BM) * (DS / 64)), dim3(256), 0, stream>>>(
        x, nullptr, nullptr, w1hi, w1lo, gu, MROWS, DS, DM, DS / 64, b_in, gamma);

    scan_partial<<<dim3(NCH, BB), dim3(256), 0, stream>>>(gu, lam, csum);
    carry_scan<<<dim3(BB), dim3(256), 0, stream>>>(csum, state, lam, carry, hlast);
    scan_final<<<dim3(NCH, BB), dim3(256), 0, stream>>>(gu, lam, carry, hhi, hlo);

    // GEMM2: y = h @ W_out + b_out  [16384 x 1024], K=256, BN=128 -> grid 1024
    mfma_gemm<false, 128><<<dim3((MROWS / BM) * (DM / 128)), dim3(256), 0, stream>>>(
        nullptr, hhi, hlo, w2hi, w2lo, y, MROWS, DM, DS, DM / 128, b_out, nullptr);
}